// Round 11
// baseline (418.878 us; speedup 1.0000x reference)
//
#include <hip/hip_runtime.h>

// GraphSAGE 2-layer. Round 18 (= round 16 kernel, third submit; rounds 16/17
// hit GPUAcquisitionTimeout before execution): launch-chain compression on
// the r14 baseline.
// (1) bucket_scan fused into conv_hist via last-hist-block-done trick
//     (device atomics + threadfence; no spin). (2) csr split: csr1 alone;
//     csr2's 196 blocks ride in the same grid as gather1 (25000 blocks) so
//     csr2 hides under the fabric-bound gather. (3) gemm1 in r14 form
//     (r15 full-A-tile halved occupancy for an illusory HBM saving —
//     A was already L2-hit). gather2 keeps r15 2-edge halves. bf16 p kept.

#define NSRC 200000
#define NMID 100000
#define NTGT 50000
#define NE1  1600000
#define NE2  800000
#define DIN  128
#define DHID 256
#define DOUT 64

#define XCH (NSRC * 16)

#define CH   4096
#define NBK1 391
#define NBK2 196
#define NCH1 ((NE1 + CH - 1) / CH)
#define NCH2 ((NE2 + CH - 1) / CH)
#define HCH  8192
#define NHC1 ((NE1 + HCH - 1) / HCH)
#define NHC2 ((NE2 + HCH - 1) / HCH)
#define NHIST (NHC1 + NHC2)
#define CVB ((XCH + 65536 + 32768 + 255) / 256)
#define MAXBUF 6144
#define G1BLK ((NMID + 3) / 4)

typedef __attribute__((ext_vector_type(8))) short bf16x8;
typedef __attribute__((ext_vector_type(4))) float f32x4;
typedef __attribute__((ext_vector_type(2))) float f32x2;

__device__ __forceinline__ unsigned short f2bf(float f) {
    unsigned int u = __builtin_bit_cast(unsigned int, f);
    u += 0x7FFFu + ((u >> 16) & 1u);
    return (unsigned short)(u >> 16);
}
__device__ __forceinline__ float bf_lo(unsigned int u) {
    return __builtin_bit_cast(float, u << 16);
}
__device__ __forceinline__ float bf_hi(unsigned int u) {
    return __builtin_bit_cast(float, u & 0xFFFF0000u);
}

// ------------ fused convert + bucket hist + (last block) scan ------------
__global__ __launch_bounds__(256) void conv_hist_kernel(
    const float* __restrict__ x,
    const float* __restrict__ Wl1, const float* __restrict__ Wr1,
    const float* __restrict__ Wl2, const float* __restrict__ Wr2,
    unsigned short* __restrict__ xb, unsigned short* __restrict__ WT1,
    unsigned short* __restrict__ WT2,
    const int* __restrict__ ei1, const int* __restrict__ ei2,
    int* __restrict__ bhist1, int* __restrict__ bhist2,
    int* __restrict__ donecnt,
    int* __restrict__ bbase1, int* __restrict__ bbase2,
    int* __restrict__ bcur1, int* __restrict__ bcur2,
    int* __restrict__ rs1, int* __restrict__ rs2)
{
    __shared__ unsigned int lh[512];
    __shared__ int sdone;
    int t = threadIdx.x;
    if (blockIdx.x < NHIST) {
        // ---- bucket histogram branch ----
        const int* ei; int* bh; int nE, nbk, chunk;
        if (blockIdx.x < NHC1) { ei = ei1; bh = bhist1; nE = NE1; nbk = NBK1; chunk = blockIdx.x; }
        else { ei = ei2; bh = bhist2; nE = NE2; nbk = NBK2; chunk = blockIdx.x - NHC1; }
        lh[t] = 0; lh[t + 256] = 0;
        __syncthreads();
        int base = chunk * HCH;
        int end = nE < base + HCH ? nE : base + HCH;
        for (int e = base + t; e < end; e += 256)
            atomicAdd(&lh[((unsigned)ei[nE + e]) >> 8], 1u);
        __syncthreads();
        if (t < nbk && lh[t]) atomicAdd(&bh[t], (int)lh[t]);
        if (t + 256 < nbk && lh[t + 256]) atomicAdd(&bh[t + 256], (int)lh[t + 256]);
        // ---- last hist block runs the exclusive scans ----
        __threadfence();
        if (t == 0) sdone = atomicAdd(donecnt, 1);
        __syncthreads();
        if (sdone != NHIST - 1) return;
        int* s = (int*)lh;
        int a0 = (2 * t < NBK1) ? atomicAdd(&bhist1[2 * t], 0) : 0;
        int a1 = (2 * t + 1 < NBK1) ? atomicAdd(&bhist1[2 * t + 1], 0) : 0;
        s[t] = a0 + a1;
        __syncthreads();
        for (int off = 1; off < 256; off <<= 1) {
            int u = (t >= off) ? s[t - off] : 0;
            __syncthreads();
            s[t] += u;
            __syncthreads();
        }
        int ex = (t > 0) ? s[t - 1] : 0;
        if (2 * t < NBK1)     { bbase1[2 * t] = ex;          bcur1[2 * t] = ex; }
        if (2 * t + 1 < NBK1) { bbase1[2 * t + 1] = ex + a0; bcur1[2 * t + 1] = ex + a0; }
        if (t == 0) { bbase1[NBK1] = NE1; rs1[NMID] = NE1; bbase2[NBK2] = NE2; rs2[NTGT] = NE2; }
        __syncthreads();
        int b0 = (t < NBK2) ? atomicAdd(&bhist2[t], 0) : 0;
        s[t] = b0;
        __syncthreads();
        for (int off = 1; off < 256; off <<= 1) {
            int u = (t >= off) ? s[t - off] : 0;
            __syncthreads();
            s[t] += u;
            __syncthreads();
        }
        int ex2 = (t > 0) ? s[t - 1] : 0;
        if (t < NBK2) { bbase2[t] = ex2; bcur2[t] = ex2; }
        return;
    }
    // ---- convert branch ----
    int gid = (blockIdx.x - NHIST) * 256 + t;
    if (gid < XCH) {
        const float4 v0 = *(const float4*)(x + (long long)gid * 8);
        const float4 v1 = *(const float4*)(x + (long long)gid * 8 + 4);
        unsigned short o[8] = {f2bf(v0.x), f2bf(v0.y), f2bf(v0.z), f2bf(v0.w),
                               f2bf(v1.x), f2bf(v1.y), f2bf(v1.z), f2bf(v1.w)};
        *(uint4*)(xb + (long long)gid * 8) = *(const uint4*)o;
        return;
    }
    int g = gid - XCH;
    if (g < 65536) {
        int n = g >> 8, k = g & 255;
        float v = (k < DIN) ? Wl1[(long long)k * DHID + n]
                            : Wr1[(long long)(k - DIN) * DHID + n];
        WT1[g] = f2bf(v);
        return;
    }
    g -= 65536;
    if (g < 32768) {
        int n2 = g >> 8, k = g & 255;
        float v = (n2 < DOUT) ? Wl2[(long long)k * DOUT + n2]
                              : Wr2[(long long)k * DOUT + (n2 - DOUT)];
        WT2[g] = f2bf(v);
    }
}

// ---------------- bin (both layers) ----------------
__global__ __launch_bounds__(256) void bin_kernel(
    const int* __restrict__ ei1, const int* __restrict__ ei2,
    int* __restrict__ bcur1, int* __restrict__ bcur2,
    uint2* __restrict__ gbuf1, uint2* __restrict__ gbuf2)
{
    __shared__ unsigned int lcnt[512];
    __shared__ unsigned int lofs[512];
    __shared__ unsigned int lpos[512];
    __shared__ unsigned int gbase[512];
    __shared__ unsigned int swarp[256];
    __shared__ uint2 lbuf[CH];

    const int* ei; int* bcur; uint2* gbuf; int nE, nbk, chunk;
    if (blockIdx.x < NCH1) {
        ei = ei1; bcur = bcur1; gbuf = gbuf1; nE = NE1; nbk = NBK1; chunk = blockIdx.x;
    } else {
        ei = ei2; bcur = bcur2; gbuf = gbuf2; nE = NE2; nbk = NBK2; chunk = blockIdx.x - NCH1;
    }
    int base = chunk * CH;
    int nb = nE - base; if (nb > CH) nb = CH;
    int t = threadIdx.x;

    for (int i = t; i < 512; i += 256) { lcnt[i] = 0; lpos[i] = 0; }
    __syncthreads();

    int srcv[16], tgtv[16];
    #pragma unroll
    for (int i = 0; i < 16; ++i) {
        int e = base + i * 256 + t;
        if (e < nE) {
            tgtv[i] = ei[nE + e];
            srcv[i] = ei[e];
            atomicAdd(&lcnt[tgtv[i] >> 8], 1u);
        } else tgtv[i] = -1;
    }
    __syncthreads();

    unsigned a0 = lcnt[2 * t], a1 = lcnt[2 * t + 1];
    swarp[t] = a0 + a1;
    __syncthreads();
    for (int off = 1; off < 256; off <<= 1) {
        unsigned v = (t >= off) ? swarp[t - off] : 0;
        __syncthreads();
        swarp[t] += v;
        __syncthreads();
    }
    unsigned ex = (t > 0) ? swarp[t - 1] : 0;
    lofs[2 * t] = ex;
    lofs[2 * t + 1] = ex + a0;
    if (2 * t < nbk && a0) gbase[2 * t] = atomicAdd(&bcur[2 * t], (int)a0);
    if (2 * t + 1 < nbk && a1) gbase[2 * t + 1] = atomicAdd(&bcur[2 * t + 1], (int)a1);
    __syncthreads();

    #pragma unroll
    for (int i = 0; i < 16; ++i) {
        if (tgtv[i] >= 0) {
            int b = tgtv[i] >> 8;
            unsigned idx = lofs[b] + atomicAdd(&lpos[b], 1u);
            lbuf[idx] = make_uint2((unsigned)srcv[i], (unsigned)tgtv[i]);
        }
    }
    __syncthreads();

    for (int i = t; i < nb; i += 256) {
        uint2 r = lbuf[i];
        int b = (int)(r.y >> 8);
        unsigned gi = gbase[b] + ((unsigned)i - lofs[b]);
        gbuf[gi] = r;
    }
}

// ---------------- layer-1 bucket CSR ----------------
__global__ __launch_bounds__(256) void csr1_kernel(
    const uint2* __restrict__ gbuf, const int* __restrict__ bbase,
    int* __restrict__ rs, int* __restrict__ csr)
{
    __shared__ unsigned int lhist[256];
    __shared__ unsigned int lcur[256];
    __shared__ unsigned int sscan[256];
    __shared__ unsigned int lbuf[MAXBUF];
    int bucket = blockIdx.x;
    int base = bbase[bucket];
    int size = bbase[bucket + 1] - base;
    int node0 = bucket << 8;
    int nnode = NMID - node0; if (nnode > 256) nnode = 256;
    int t = threadIdx.x;
    lhist[t] = 0;
    __syncthreads();
    for (int i = t; i < size; i += 256)
        atomicAdd(&lhist[gbuf[base + i].y & 255], 1u);
    __syncthreads();
    unsigned v = lhist[t];
    sscan[t] = v;
    __syncthreads();
    for (int off = 1; off < 256; off <<= 1) {
        unsigned u = (t >= off) ? sscan[t - off] : 0;
        __syncthreads();
        sscan[t] += u;
        __syncthreads();
    }
    unsigned ex = (t > 0) ? sscan[t - 1] : 0;
    lcur[t] = ex;
    if (t < nnode) rs[node0 + t] = base + (int)ex;
    __syncthreads();
    for (int i = t; i < size; i += 256) {
        uint2 r = gbuf[base + i];
        unsigned pos = atomicAdd(&lcur[r.y & 255], 1u);
        lbuf[pos] = r.x;
    }
    __syncthreads();
    for (int i = t; i < size; i += 256)
        csr[base + i] = (int)lbuf[i];
}

// -------- combined: layer-2 bucket CSR (196 blocks) + gather1 (25000) ------
// gather1 only needs csr1/rs1 (previous launch); csr2 runs concurrently and
// hides under the fabric-bound gather. gather branch: round-8 form (node in
// SGPR => rs/csr via s_load; row loads via saddr; 4 loads in flight).
__global__ __launch_bounds__(256) void csr2_gather1_kernel(
    const uint2* __restrict__ gbuf2, const int* __restrict__ bbase2,
    int* __restrict__ rs2, int* __restrict__ csr2,
    const unsigned short* __restrict__ xb, const int* __restrict__ rs1,
    const int* __restrict__ csr1, unsigned short* __restrict__ aggnb)
{
    __shared__ unsigned int lhist[256];
    __shared__ unsigned int lcur[256];
    __shared__ unsigned int sscan[256];
    __shared__ unsigned int lbuf[MAXBUF];
    int t = threadIdx.x;
    if (blockIdx.x < NBK2) {
        int bucket = blockIdx.x;
        int base = bbase2[bucket];
        int size = bbase2[bucket + 1] - base;
        int node0 = bucket << 8;
        int nnode = NTGT - node0; if (nnode > 256) nnode = 256;
        lhist[t] = 0;
        __syncthreads();
        for (int i = t; i < size; i += 256)
            atomicAdd(&lhist[gbuf2[base + i].y & 255], 1u);
        __syncthreads();
        unsigned v = lhist[t];
        sscan[t] = v;
        __syncthreads();
        for (int off = 1; off < 256; off <<= 1) {
            unsigned u = (t >= off) ? sscan[t - off] : 0;
            __syncthreads();
            sscan[t] += u;
            __syncthreads();
        }
        unsigned ex = (t > 0) ? sscan[t - 1] : 0;
        lcur[t] = ex;
        if (t < nnode) rs2[node0 + t] = base + (int)ex;
        __syncthreads();
        for (int i = t; i < size; i += 256) {
            uint2 r = gbuf2[base + i];
            unsigned pos = atomicAdd(&lcur[r.y & 255], 1u);
            lbuf[pos] = r.x;
        }
        __syncthreads();
        for (int i = t; i < size; i += 256)
            csr2[base + i] = (int)lbuf[i];
        return;
    }
    // ---- gather1 branch ----
    int wid = t >> 6;
    int lane = t & 63;
    int node = __builtin_amdgcn_readfirstlane((blockIdx.x - NBK2) * 4 + wid);
    if (node >= NMID) return;
    int s = rs1[node];
    int d = rs1[node + 1] - s;
    const unsigned int* xw = (const unsigned int*)xb;   // 64 uints per row
    f32x2 a0 = {0.f, 0.f}, a1 = {0.f, 0.f}, a2 = {0.f, 0.f}, a3 = {0.f, 0.f};
    int j = 0;
    for (; j + 3 < d; j += 4) {
        int i0 = csr1[s + j];
        int i1 = csr1[s + j + 1];
        int i2 = csr1[s + j + 2];
        int i3 = csr1[s + j + 3];
        unsigned int u0 = xw[((size_t)(unsigned)i0 << 6) + lane];
        unsigned int u1 = xw[((size_t)(unsigned)i1 << 6) + lane];
        unsigned int u2 = xw[((size_t)(unsigned)i2 << 6) + lane];
        unsigned int u3 = xw[((size_t)(unsigned)i3 << 6) + lane];
        a0 += (f32x2){bf_lo(u0), bf_hi(u0)};
        a1 += (f32x2){bf_lo(u1), bf_hi(u1)};
        a2 += (f32x2){bf_lo(u2), bf_hi(u2)};
        a3 += (f32x2){bf_lo(u3), bf_hi(u3)};
    }
    for (; j < d; ++j) {
        int i0 = csr1[s + j];
        unsigned int u0 = xw[((size_t)(unsigned)i0 << 6) + lane];
        a0 += (f32x2){bf_lo(u0), bf_hi(u0)};
    }
    float inv = (d > 0) ? 1.0f / (float)d : 0.f;
    f32x2 r = (a0 + a1) + (a2 + a3);
    unsigned int packed =
        (unsigned int)f2bf(r.x * inv) | ((unsigned int)f2bf(r.y * inv) << 16);
    *(unsigned int*)(aggnb + (long long)node * DIN + lane * 2) = packed;
}

// out[node] = q[node] + mean_{src} p[src]; p is bf16 (64 cols = 32 uints/row).
// Two edges per wave: 32-lane halves each cover a full row (2 cols per lane).
__global__ __launch_bounds__(256) void gather2_final_kernel(
    const unsigned short* __restrict__ pb, const float* __restrict__ qb,
    const int* __restrict__ rs, const int* __restrict__ csr,
    float* __restrict__ out)
{
    int wid = threadIdx.x >> 6;
    int lane = threadIdx.x & 63;
    int hh = lane >> 5;      // half-wave id (0/1)
    int c  = lane & 31;      // uint index within row (2 cols per lane)
    int node = __builtin_amdgcn_readfirstlane(blockIdx.x * 4 + wid);
    if (node >= NTGT) return;
    int s = rs[node];
    int d = rs[node + 1] - s;
    const unsigned int* pw = (const unsigned int*)pb;   // 32 uints per row
    f32x2 a0 = {0.f, 0.f}, a1 = {0.f, 0.f}, a2 = {0.f, 0.f}, a3 = {0.f, 0.f};
    int j = 0;
    for (; j + 8 <= d; j += 8) {
        int e0 = csr[s + j + 0], e1 = csr[s + j + 1];
        int e2 = csr[s + j + 2], e3 = csr[s + j + 3];
        int e4 = csr[s + j + 4], e5 = csr[s + j + 5];
        int e6 = csr[s + j + 6], e7 = csr[s + j + 7];
        int i0 = hh ? e1 : e0;
        int i1 = hh ? e3 : e2;
        int i2 = hh ? e5 : e4;
        int i3 = hh ? e7 : e6;
        unsigned u0 = pw[((size_t)(unsigned)i0 << 5) + c];
        unsigned u1 = pw[((size_t)(unsigned)i1 << 5) + c];
        unsigned u2 = pw[((size_t)(unsigned)i2 << 5) + c];
        unsigned u3 = pw[((size_t)(unsigned)i3 << 5) + c];
        a0 += (f32x2){bf_lo(u0), bf_hi(u0)};
        a1 += (f32x2){bf_lo(u1), bf_hi(u1)};
        a2 += (f32x2){bf_lo(u2), bf_hi(u2)};
        a3 += (f32x2){bf_lo(u3), bf_hi(u3)};
    }
    for (; j < d; j += 2) {
        int rem = d - j;             // 1 or >=2
        int ea = csr[s + j];
        int eb = (rem > 1) ? csr[s + j + 1] : ea;
        if (hh < rem) {
            int ia = hh ? eb : ea;
            unsigned ua = pw[((size_t)(unsigned)ia << 5) + c];
            a0 += (f32x2){bf_lo(ua), bf_hi(ua)};
        }
    }
    f32x2 tt = (a0 + a1) + (a2 + a3);
    tt.x += __shfl_xor(tt.x, 32);
    tt.y += __shfl_xor(tt.y, 32);
    if (hh == 0) {
        float inv = (d > 0) ? 1.0f / (float)d : 0.f;
        const float2 qv = *(const float2*)(qb + (long long)node * DOUT + c * 2);
        float2 o;
        o.x = qv.x + tt.x * inv;
        o.y = qv.y + tt.y * inv;
        *(float2*)(out + (long long)node * DOUT + c * 2) = o;
    }
}

// ---------------- MFMA GEMMs (round-14 forms) ----------------
#define LDSP 40

// h = relu([aggnb|xb] @ WT1^T + b1), register-prefetch pipelined
__global__ __launch_bounds__(256) void gemm1_mfma(
    const unsigned short* __restrict__ aggnb, const unsigned short* __restrict__ xb,
    const unsigned short* __restrict__ WT, const float* __restrict__ bias,
    unsigned short* __restrict__ h)
{
    __shared__ unsigned short Asm[128 * LDSP];
    __shared__ unsigned short Bsm[128 * LDSP];
    const int tid = threadIdx.x;
    const int bm = blockIdx.x * 128;
    const int bn = blockIdx.y * 128;
    const int wave = tid >> 6, lane = tid & 63;
    const int wr = wave >> 1, wc = wave & 1;
    const int lrow = lane & 15, quad = lane >> 4;

    const int c0r = tid >> 2, c0s = tid & 3;
    const int c1r = (tid + 256) >> 2, c1s = tid & 3;
    int growA0 = bm + c0r; if (growA0 >= NMID) growA0 = NMID - 1;
    int growA1 = bm + c1r; if (growA1 >= NMID) growA1 = NMID - 1;

    uint4 pa0, pa1, pb0, pb1;
    auto gload = [&](int k0) {
        int gk0 = k0 + c0s * 8;
        const unsigned short* sA0 = (gk0 < DIN)
            ? (aggnb + (long long)growA0 * DIN + gk0)
            : (xb + (long long)growA0 * DIN + (gk0 - DIN));
        pa0 = *(const uint4*)sA0;
        const unsigned short* sA1 = (gk0 < DIN)
            ? (aggnb + (long long)growA1 * DIN + gk0)
            : (xb + (long long)growA1 * DIN + (gk0 - DIN));
        pa1 = *(const uint4*)sA1;
        pb0 = *(const uint4*)(WT + (long long)(bn + c0r) * 256 + k0 + c0s * 8);
        pb1 = *(const uint4*)(WT + (long long)(bn + c1r) * 256 + k0 + c1s * 8);
    };

    f32x4 acc[4][4];
    #pragma unroll
    for (int i = 0; i < 4; ++i)
        #pragma unroll
        for (int j = 0; j < 4; ++j)
            acc[i][j] = (f32x4){0.f, 0.f, 0.f, 0.f};

    gload(0);
    for (int it = 0; it < 8; ++it) {
        if (it) __syncthreads();
        *(uint4*)(Asm + c0r * LDSP + c0s * 8) = pa0;
        *(uint4*)(Asm + c1r * LDSP + c1s * 8) = pa1;
        *(uint4*)(Bsm + c0r * LDSP + c0s * 8) = pb0;
        *(uint4*)(Bsm + c1r * LDSP + c1s * 8) = pb1;
        __syncthreads();
        if (it < 7) gload((it + 1) * 32);
        bf16x8 af[4], bfr[4];
        #pragma unroll
        for (int mi = 0; mi < 4; ++mi)
            af[mi] = *(const bf16x8*)(Asm + (wr * 64 + mi * 16 + lrow) * LDSP + quad * 8);
        #pragma unroll
        for (int ni = 0; ni < 4; ++ni)
            bfr[ni] = *(const bf16x8*)(Bsm + (wc * 64 + ni * 16 + lrow) * LDSP + quad * 8);
        #pragma unroll
        for (int mi = 0; mi < 4; ++mi)
            #pragma unroll
            for (int ni = 0; ni < 4; ++ni)
                acc[mi][ni] = __builtin_amdgcn_mfma_f32_16x16x32_bf16(
                    af[mi], bfr[ni], acc[mi][ni], 0, 0, 0);
    }
    #pragma unroll
    for (int mi = 0; mi < 4; ++mi) {
        #pragma unroll
        for (int ni = 0; ni < 4; ++ni) {
            int col = bn + wc * 64 + ni * 16 + lrow;
            float bv = bias[col];
            #pragma unroll
            for (int r = 0; r < 4; ++r) {
                int row = bm + wr * 64 + mi * 16 + quad * 4 + r;
                if (row < NMID) {
                    float v = acc[mi][ni][r] + bv;
                    h[(long long)row * DHID + col] = f2bf(fmaxf(v, 0.0f));
                }
            }
        }
    }
}

// p = h @ Wl2 (all rows, bf16 out); q = h @ Wr2 + b2 (rows < NTGT, f32 out).
__global__ __launch_bounds__(256) void gemm2_dual_mfma(
    const unsigned short* __restrict__ h, const unsigned short* __restrict__ WT2,
    const float* __restrict__ b2,
    unsigned short* __restrict__ pb, float* __restrict__ qb)
{
    __shared__ unsigned short Asm[128 * LDSP];
    __shared__ unsigned short Bsm[128 * LDSP];
    const int tid = threadIdx.x;
    const int bm = blockIdx.x * 128;
    const int wave = tid >> 6, lane = tid & 63;
    const int lrow = lane & 15, quad = lane >> 4;
    const bool doq = (bm < NTGT);

    const int c0r = tid >> 2, c0s = tid & 3;
    const int c1r = (tid + 256) >> 2;
    int growA0 = bm + c0r; if (growA0 >= NMID) growA0 = NMID - 1;
    int growA1 = bm + c1r; if (growA1 >= NMID) growA1 = NMID - 1;

    uint4 pa0, pa1, pb0, pb1;
    auto gload = [&](int k0) {
        pa0 = *(const uint4*)(h + (long long)growA0 * DHID + k0 + c0s * 8);
        pa1 = *(const uint4*)(h + (long long)growA1 * DHID + k0 + c0s * 8);
        pb0 = *(const uint4*)(WT2 + (long long)c0r * 256 + k0 + c0s * 8);
        pb1 = *(const uint4*)(WT2 + (long long)c1r * 256 + k0 + c0s * 8);
    };

    f32x4 accP[2][4], accQ[2][4];
    #pragma unroll
    for (int i = 0; i < 2; ++i)
        #pragma unroll
        for (int j = 0; j < 4; ++j) {
            accP[i][j] = (f32x4){0.f, 0.f, 0.f, 0.f};
            accQ[i][j] = (f32x4){0.f, 0.f, 0.f, 0.f};
        }

    gload(0);
    for (int it = 0; it < 8; ++it) {
        if (it) __syncthreads();
        *(uint4*)(Asm + c0r * LDSP + c0s * 8) = pa0;
        *(uint4*)(Asm + c1r * LDSP + c0s * 8) = pa1;
        *(uint4*)(Bsm + c0r * LDSP + c0s * 8) = pb0;
        *(uint4*)(Bsm + c1r * LDSP + c0s * 8) = pb1;
        __syncthreads();
        if (it < 7) gload((it + 1) * 32);
        bf16x8 af[2], bp[4];
        #pragma unroll
        for (int mi = 0; mi < 2; ++mi)
            af[mi] = *(const bf16x8*)(Asm + (wave * 32 + mi * 16 + lrow) * LDSP + quad * 8);
        #pragma unroll
        for (int ni = 0; ni < 4; ++ni)
            bp[ni] = *(const bf16x8*)(Bsm + (ni * 16 + lrow) * LDSP + quad * 8);
        #pragma unroll
        for (int mi = 0; mi < 2; ++mi)
            #pragma unroll
            for (int ni = 0; ni < 4; ++ni)
                accP[mi][ni] = __builtin_amdgcn_mfma_f32_16x16x32_bf16(
                    af[mi], bp[ni], accP[mi][ni], 0, 0, 0);
        if (doq) {
            bf16x8 bq[4];
            #pragma unroll
            for (int ni = 0; ni < 4; ++ni)
                bq[ni] = *(const bf16x8*)(Bsm + (64 + ni * 16 + lrow) * LDSP + quad * 8);
            #pragma unroll
            for (int mi = 0; mi < 2; ++mi)
                #pragma unroll
                for (int ni = 0; ni < 4; ++ni)
                    accQ[mi][ni] = __builtin_amdgcn_mfma_f32_16x16x32_bf16(
                        af[mi], bq[ni], accQ[mi][ni], 0, 0, 0);
        }
    }
    #pragma unroll
    for (int mi = 0; mi < 2; ++mi) {
        #pragma unroll
        for (int ni = 0; ni < 4; ++ni) {
            int col = ni * 16 + lrow;
            #pragma unroll
            for (int r = 0; r < 4; ++r) {
                int row = bm + wave * 32 + mi * 16 + quad * 4 + r;
                if (row < NMID)
                    pb[(long long)row * DOUT + col] = f2bf(accP[mi][ni][r]);
                if (doq && row < NTGT)
                    qb[(long long)row * DOUT + col] = accQ[mi][ni][r] + b2[col];
            }
        }
    }
}

extern "C" void kernel_launch(void* const* d_in, const int* in_sizes, int n_in,
                              void* d_out, int out_size, void* d_ws, size_t ws_size,
                              hipStream_t stream) {
    const float* x   = (const float*)d_in[0];
    const int*   ei1 = (const int*)d_in[1];
    const int*   ei2 = (const int*)d_in[2];
    const float* Wl1 = (const float*)d_in[3];
    const float* Wr1 = (const float*)d_in[4];
    const float* b1  = (const float*)d_in[5];
    const float* Wl2 = (const float*)d_in[6];
    const float* Wr2 = (const float*)d_in[7];
    const float* b2  = (const float*)d_in[8];
    float* out = (float*)d_out;

    unsigned short* xb    = (unsigned short*)d_ws;
    unsigned short* aggnb = xb + (size_t)NSRC * DIN;
    unsigned short* h     = aggnb + (size_t)NMID * DIN;
    unsigned short* WT1   = h + (size_t)NMID * DHID;
    unsigned short* WT2   = WT1 + 256 * 256;
    unsigned short* pb    = WT2 + 128 * 256;              // bf16 p: NMID x 64
    float* qb    = (float*)(pb + (size_t)NMID * DOUT);
    int* rs1     = (int*)(qb + (size_t)NTGT * DOUT);
    int* rs2     = rs1 + (NMID + 1);
    int* bhist1  = rs2 + (NTGT + 1);
    int* bhist2  = bhist1 + NBK1;
    int* donecnt = bhist2 + NBK2;
    int* bbase1  = donecnt + 1;
    int* bbase2  = bbase1 + (NBK1 + 1);
    int* bcur1   = bbase2 + (NBK2 + 1);
    int* bcur2   = bcur1 + NBK1;
    int* csr1    = bcur2 + NBK2 + 1;
    int* csr2    = csr1 + NE1;
    uint2* gbuf1 = (uint2*)(((size_t)(csr2 + NE2) + 15) & ~(size_t)15);
    uint2* gbuf2 = gbuf1 + NE1;

    // zero bhist1, bhist2, donecnt (contiguous)
    hipMemsetAsync(bhist1, 0, (size_t)(NBK1 + NBK2 + 1) * 4, stream);
    conv_hist_kernel<<<NHIST + CVB, 256, 0, stream>>>(
        x, Wl1, Wr1, Wl2, Wr2, xb, WT1, WT2, ei1, ei2, bhist1, bhist2,
        donecnt, bbase1, bbase2, bcur1, bcur2, rs1, rs2);
    bin_kernel<<<NCH1 + NCH2, 256, 0, stream>>>(ei1, ei2, bcur1, bcur2, gbuf1, gbuf2);
    csr1_kernel<<<NBK1, 256, 0, stream>>>(gbuf1, bbase1, rs1, csr1);
    csr2_gather1_kernel<<<NBK2 + G1BLK, 256, 0, stream>>>(
        gbuf2, bbase2, rs2, csr2, xb, rs1, csr1, aggnb);
    {
        dim3 grid((NMID + 127) / 128, 2);
        gemm1_mfma<<<grid, 256, 0, stream>>>(aggnb, xb, WT1, b1, h);
    }
    gemm2_dual_mfma<<<(NMID + 127) / 128, 256, 0, stream>>>(h, WT2, b2, pb, qb);
    gather2_final_kernel<<<(NTGT + 3) / 4, 256, 0, stream>>>(pb, qb, rs2, csr2, out);
}

// Round 12
// 405.354 us; speedup vs baseline: 1.0334x; 1.0334x over previous
//
#include <hip/hip_runtime.h>

// GraphSAGE 2-layer. Round 19: revert to round-14 structure (best measured
// 389.3us). r16's csr2+gather1 fusion REGRESSED (80us, occupancy 70->43%,
// BW 3.7->2.9 TB/s): gather1 needs full occupancy for MLP -> never co-locate
// LDS-heavy branches with it. Only r16 survivor: bucket_scan fused into
// conv_hist's last hist block (launch count -1, no occupancy impact).
// Forms: standalone bucket_csr (both layers), r8 gather1 (VGPR12/LDS0),
// r14 gemm1 (grid.y=2), r14 gemm2_dual (bf16 p), r14 gather2 (4-wide).

#define NSRC 200000
#define NMID 100000
#define NTGT 50000
#define NE1  1600000
#define NE2  800000
#define DIN  128
#define DHID 256
#define DOUT 64

#define XCH (NSRC * 16)

#define CH   4096
#define NBK1 391
#define NBK2 196
#define NCH1 ((NE1 + CH - 1) / CH)
#define NCH2 ((NE2 + CH - 1) / CH)
#define HCH  8192
#define NHC1 ((NE1 + HCH - 1) / HCH)
#define NHC2 ((NE2 + HCH - 1) / HCH)
#define NHIST (NHC1 + NHC2)
#define CVB ((XCH + 65536 + 32768 + 255) / 256)
#define MAXBUF 6144

typedef __attribute__((ext_vector_type(8))) short bf16x8;
typedef __attribute__((ext_vector_type(4))) float f32x4;
typedef __attribute__((ext_vector_type(2))) float f32x2;

__device__ __forceinline__ unsigned short f2bf(float f) {
    unsigned int u = __builtin_bit_cast(unsigned int, f);
    u += 0x7FFFu + ((u >> 16) & 1u);
    return (unsigned short)(u >> 16);
}
__device__ __forceinline__ float bf_lo(unsigned int u) {
    return __builtin_bit_cast(float, u << 16);
}
__device__ __forceinline__ float bf_hi(unsigned int u) {
    return __builtin_bit_cast(float, u & 0xFFFF0000u);
}
__device__ __forceinline__ float bf1(unsigned short u) {
    return __builtin_bit_cast(float, (unsigned int)u << 16);
}

// ------------ fused convert + bucket hist + (last block) scan ------------
__global__ __launch_bounds__(256) void conv_hist_kernel(
    const float* __restrict__ x,
    const float* __restrict__ Wl1, const float* __restrict__ Wr1,
    const float* __restrict__ Wl2, const float* __restrict__ Wr2,
    unsigned short* __restrict__ xb, unsigned short* __restrict__ WT1,
    unsigned short* __restrict__ WT2,
    const int* __restrict__ ei1, const int* __restrict__ ei2,
    int* __restrict__ bhist1, int* __restrict__ bhist2,
    int* __restrict__ donecnt,
    int* __restrict__ bbase1, int* __restrict__ bbase2,
    int* __restrict__ bcur1, int* __restrict__ bcur2,
    int* __restrict__ rs1, int* __restrict__ rs2)
{
    __shared__ unsigned int lh[512];
    __shared__ int sdone;
    int t = threadIdx.x;
    if (blockIdx.x < NHIST) {
        // ---- bucket histogram branch ----
        const int* ei; int* bh; int nE, nbk, chunk;
        if (blockIdx.x < NHC1) { ei = ei1; bh = bhist1; nE = NE1; nbk = NBK1; chunk = blockIdx.x; }
        else { ei = ei2; bh = bhist2; nE = NE2; nbk = NBK2; chunk = blockIdx.x - NHC1; }
        lh[t] = 0; lh[t + 256] = 0;
        __syncthreads();
        int base = chunk * HCH;
        int end = nE < base + HCH ? nE : base + HCH;
        for (int e = base + t; e < end; e += 256)
            atomicAdd(&lh[((unsigned)ei[nE + e]) >> 8], 1u);
        __syncthreads();
        if (t < nbk && lh[t]) atomicAdd(&bh[t], (int)lh[t]);
        if (t + 256 < nbk && lh[t + 256]) atomicAdd(&bh[t + 256], (int)lh[t + 256]);
        // ---- last hist block runs the exclusive scans ----
        __threadfence();
        if (t == 0) sdone = atomicAdd(donecnt, 1);
        __syncthreads();
        if (sdone != NHIST - 1) return;
        int* s = (int*)lh;
        int a0 = (2 * t < NBK1) ? atomicAdd(&bhist1[2 * t], 0) : 0;
        int a1 = (2 * t + 1 < NBK1) ? atomicAdd(&bhist1[2 * t + 1], 0) : 0;
        s[t] = a0 + a1;
        __syncthreads();
        for (int off = 1; off < 256; off <<= 1) {
            int u = (t >= off) ? s[t - off] : 0;
            __syncthreads();
            s[t] += u;
            __syncthreads();
        }
        int ex = (t > 0) ? s[t - 1] : 0;
        if (2 * t < NBK1)     { bbase1[2 * t] = ex;          bcur1[2 * t] = ex; }
        if (2 * t + 1 < NBK1) { bbase1[2 * t + 1] = ex + a0; bcur1[2 * t + 1] = ex + a0; }
        if (t == 0) { bbase1[NBK1] = NE1; rs1[NMID] = NE1; bbase2[NBK2] = NE2; rs2[NTGT] = NE2; }
        __syncthreads();
        int b0 = (t < NBK2) ? atomicAdd(&bhist2[t], 0) : 0;
        s[t] = b0;
        __syncthreads();
        for (int off = 1; off < 256; off <<= 1) {
            int u = (t >= off) ? s[t - off] : 0;
            __syncthreads();
            s[t] += u;
            __syncthreads();
        }
        int ex2 = (t > 0) ? s[t - 1] : 0;
        if (t < NBK2) { bbase2[t] = ex2; bcur2[t] = ex2; }
        return;
    }
    // ---- convert branch ----
    int gid = (blockIdx.x - NHIST) * 256 + t;
    if (gid < XCH) {
        const float4 v0 = *(const float4*)(x + (long long)gid * 8);
        const float4 v1 = *(const float4*)(x + (long long)gid * 8 + 4);
        unsigned short o[8] = {f2bf(v0.x), f2bf(v0.y), f2bf(v0.z), f2bf(v0.w),
                               f2bf(v1.x), f2bf(v1.y), f2bf(v1.z), f2bf(v1.w)};
        *(uint4*)(xb + (long long)gid * 8) = *(const uint4*)o;
        return;
    }
    int g = gid - XCH;
    if (g < 65536) {
        int n = g >> 8, k = g & 255;
        float v = (k < DIN) ? Wl1[(long long)k * DHID + n]
                            : Wr1[(long long)(k - DIN) * DHID + n];
        WT1[g] = f2bf(v);
        return;
    }
    g -= 65536;
    if (g < 32768) {
        int n2 = g >> 8, k = g & 255;
        float v = (n2 < DOUT) ? Wl2[(long long)k * DOUT + n2]
                              : Wr2[(long long)k * DOUT + (n2 - DOUT)];
        WT2[g] = f2bf(v);
    }
}

// ---------------- bin (both layers) ----------------
__global__ __launch_bounds__(256) void bin_kernel(
    const int* __restrict__ ei1, const int* __restrict__ ei2,
    int* __restrict__ bcur1, int* __restrict__ bcur2,
    uint2* __restrict__ gbuf1, uint2* __restrict__ gbuf2)
{
    __shared__ unsigned int lcnt[512];
    __shared__ unsigned int lofs[512];
    __shared__ unsigned int lpos[512];
    __shared__ unsigned int gbase[512];
    __shared__ unsigned int swarp[256];
    __shared__ uint2 lbuf[CH];

    const int* ei; int* bcur; uint2* gbuf; int nE, nbk, chunk;
    if (blockIdx.x < NCH1) {
        ei = ei1; bcur = bcur1; gbuf = gbuf1; nE = NE1; nbk = NBK1; chunk = blockIdx.x;
    } else {
        ei = ei2; bcur = bcur2; gbuf = gbuf2; nE = NE2; nbk = NBK2; chunk = blockIdx.x - NCH1;
    }
    int base = chunk * CH;
    int nb = nE - base; if (nb > CH) nb = CH;
    int t = threadIdx.x;

    for (int i = t; i < 512; i += 256) { lcnt[i] = 0; lpos[i] = 0; }
    __syncthreads();

    int srcv[16], tgtv[16];
    #pragma unroll
    for (int i = 0; i < 16; ++i) {
        int e = base + i * 256 + t;
        if (e < nE) {
            tgtv[i] = ei[nE + e];
            srcv[i] = ei[e];
            atomicAdd(&lcnt[tgtv[i] >> 8], 1u);
        } else tgtv[i] = -1;
    }
    __syncthreads();

    unsigned a0 = lcnt[2 * t], a1 = lcnt[2 * t + 1];
    swarp[t] = a0 + a1;
    __syncthreads();
    for (int off = 1; off < 256; off <<= 1) {
        unsigned v = (t >= off) ? swarp[t - off] : 0;
        __syncthreads();
        swarp[t] += v;
        __syncthreads();
    }
    unsigned ex = (t > 0) ? swarp[t - 1] : 0;
    lofs[2 * t] = ex;
    lofs[2 * t + 1] = ex + a0;
    if (2 * t < nbk && a0) gbase[2 * t] = atomicAdd(&bcur[2 * t], (int)a0);
    if (2 * t + 1 < nbk && a1) gbase[2 * t + 1] = atomicAdd(&bcur[2 * t + 1], (int)a1);
    __syncthreads();

    #pragma unroll
    for (int i = 0; i < 16; ++i) {
        if (tgtv[i] >= 0) {
            int b = tgtv[i] >> 8;
            unsigned idx = lofs[b] + atomicAdd(&lpos[b], 1u);
            lbuf[idx] = make_uint2((unsigned)srcv[i], (unsigned)tgtv[i]);
        }
    }
    __syncthreads();

    for (int i = t; i < nb; i += 256) {
        uint2 r = lbuf[i];
        int b = (int)(r.y >> 8);
        unsigned gi = gbase[b] + ((unsigned)i - lofs[b]);
        gbuf[gi] = r;
    }
}

// ---------------- bucket CSR (both layers) ----------------
__global__ __launch_bounds__(256) void bucket_csr_kernel(
    const uint2* __restrict__ gbuf1, const uint2* __restrict__ gbuf2,
    const int* __restrict__ bbase1, const int* __restrict__ bbase2,
    int* __restrict__ rs1, int* __restrict__ rs2,
    int* __restrict__ csr1, int* __restrict__ csr2)
{
    __shared__ unsigned int lhist[256];
    __shared__ unsigned int lcur[256];
    __shared__ unsigned int sscan[256];
    __shared__ unsigned int lbuf[MAXBUF];
    const uint2* gbuf; const int* bbase; int* rs; int* csr; int bucket, ntot;
    if (blockIdx.x < NBK1) {
        gbuf = gbuf1; bbase = bbase1; rs = rs1; csr = csr1; bucket = blockIdx.x; ntot = NMID;
    } else {
        gbuf = gbuf2; bbase = bbase2; rs = rs2; csr = csr2; bucket = blockIdx.x - NBK1; ntot = NTGT;
    }
    int base = bbase[bucket];
    int size = bbase[bucket + 1] - base;
    int node0 = bucket << 8;
    int nnode = ntot - node0; if (nnode > 256) nnode = 256;
    int t = threadIdx.x;
    lhist[t] = 0;
    __syncthreads();
    for (int i = t; i < size; i += 256)
        atomicAdd(&lhist[gbuf[base + i].y & 255], 1u);
    __syncthreads();
    unsigned v = lhist[t];
    sscan[t] = v;
    __syncthreads();
    for (int off = 1; off < 256; off <<= 1) {
        unsigned u = (t >= off) ? sscan[t - off] : 0;
        __syncthreads();
        sscan[t] += u;
        __syncthreads();
    }
    unsigned ex = (t > 0) ? sscan[t - 1] : 0;
    lcur[t] = ex;
    if (t < nnode) rs[node0 + t] = base + (int)ex;
    __syncthreads();
    for (int i = t; i < size; i += 256) {
        uint2 r = gbuf[base + i];
        unsigned pos = atomicAdd(&lcur[r.y & 255], 1u);
        lbuf[pos] = r.x;
    }
    __syncthreads();
    for (int i = t; i < size; i += 256)
        csr[base + i] = (int)lbuf[i];
}

// ---------------- gathers (round-8 form: scalarized, 4-wide) ----------------
// One wave per node. node forced into SGPR so rs/csr reads are s_load and row
// loads use the saddr form (zero per-edge VALU address math).

__global__ __launch_bounds__(256) void gather1_kernel(
    const unsigned short* __restrict__ xb, const int* __restrict__ rs,
    const int* __restrict__ csr, unsigned short* __restrict__ aggnb)
{
    int wid = threadIdx.x >> 6;
    int lane = threadIdx.x & 63;
    int node = __builtin_amdgcn_readfirstlane(blockIdx.x * 4 + wid);
    if (node >= NMID) return;
    int s = rs[node];
    int d = rs[node + 1] - s;
    const unsigned int* xw = (const unsigned int*)xb;   // 64 uints per row
    f32x2 a0 = {0.f, 0.f}, a1 = {0.f, 0.f}, a2 = {0.f, 0.f}, a3 = {0.f, 0.f};
    int j = 0;
    for (; j + 3 < d; j += 4) {
        int i0 = csr[s + j];
        int i1 = csr[s + j + 1];
        int i2 = csr[s + j + 2];
        int i3 = csr[s + j + 3];
        unsigned int u0 = xw[((size_t)(unsigned)i0 << 6) + lane];
        unsigned int u1 = xw[((size_t)(unsigned)i1 << 6) + lane];
        unsigned int u2 = xw[((size_t)(unsigned)i2 << 6) + lane];
        unsigned int u3 = xw[((size_t)(unsigned)i3 << 6) + lane];
        a0 += (f32x2){bf_lo(u0), bf_hi(u0)};
        a1 += (f32x2){bf_lo(u1), bf_hi(u1)};
        a2 += (f32x2){bf_lo(u2), bf_hi(u2)};
        a3 += (f32x2){bf_lo(u3), bf_hi(u3)};
    }
    for (; j < d; ++j) {
        int i0 = csr[s + j];
        unsigned int u0 = xw[((size_t)(unsigned)i0 << 6) + lane];
        a0 += (f32x2){bf_lo(u0), bf_hi(u0)};
    }
    float inv = (d > 0) ? 1.0f / (float)d : 0.f;
    f32x2 r = (a0 + a1) + (a2 + a3);
    float r0 = r.x * inv;
    float r1 = r.y * inv;
    unsigned int packed = (unsigned int)f2bf(r0) | ((unsigned int)f2bf(r1) << 16);
    *(unsigned int*)(aggnb + (long long)node * DIN + lane * 2) = packed;
}

// out[node] = q[node] + mean_{src in N(node)} p[src]; p is bf16 (64/row)
__global__ __launch_bounds__(256) void gather2_final_kernel(
    const unsigned short* __restrict__ pb, const float* __restrict__ qb,
    const int* __restrict__ rs, const int* __restrict__ csr,
    float* __restrict__ out)
{
    int wid = threadIdx.x >> 6;
    int lane = threadIdx.x & 63;
    int node = __builtin_amdgcn_readfirstlane(blockIdx.x * 4 + wid);
    if (node >= NTGT) return;
    int s = rs[node];
    int d = rs[node + 1] - s;
    float a0 = 0.f, a1 = 0.f, a2 = 0.f, a3 = 0.f;
    int j = 0;
    for (; j + 3 < d; j += 4) {
        int i0 = csr[s + j];
        int i1 = csr[s + j + 1];
        int i2 = csr[s + j + 2];
        int i3 = csr[s + j + 3];
        a0 += bf1(pb[((size_t)(unsigned)i0 << 6) + lane]);
        a1 += bf1(pb[((size_t)(unsigned)i1 << 6) + lane]);
        a2 += bf1(pb[((size_t)(unsigned)i2 << 6) + lane]);
        a3 += bf1(pb[((size_t)(unsigned)i3 << 6) + lane]);
    }
    for (; j < d; ++j) {
        int i0 = csr[s + j];
        a0 += bf1(pb[((size_t)(unsigned)i0 << 6) + lane]);
    }
    float inv = (d > 0) ? 1.0f / (float)d : 0.f;
    out[(long long)node * DOUT + lane] =
        qb[(long long)node * DOUT + lane] + ((a0 + a1) + (a2 + a3)) * inv;
}

// ---------------- MFMA GEMMs (round-14 forms) ----------------
#define LDSP 40

// h = relu([aggnb|xb] @ WT1^T + b1), register-prefetch pipelined
__global__ __launch_bounds__(256) void gemm1_mfma(
    const unsigned short* __restrict__ aggnb, const unsigned short* __restrict__ xb,
    const unsigned short* __restrict__ WT, const float* __restrict__ bias,
    unsigned short* __restrict__ h)
{
    __shared__ unsigned short Asm[128 * LDSP];
    __shared__ unsigned short Bsm[128 * LDSP];
    const int tid = threadIdx.x;
    const int bm = blockIdx.x * 128;
    const int bn = blockIdx.y * 128;
    const int wave = tid >> 6, lane = tid & 63;
    const int wr = wave >> 1, wc = wave & 1;
    const int lrow = lane & 15, quad = lane >> 4;

    const int c0r = tid >> 2, c0s = tid & 3;
    const int c1r = (tid + 256) >> 2, c1s = tid & 3;
    int growA0 = bm + c0r; if (growA0 >= NMID) growA0 = NMID - 1;
    int growA1 = bm + c1r; if (growA1 >= NMID) growA1 = NMID - 1;

    uint4 pa0, pa1, pb0, pb1;
    auto gload = [&](int k0) {
        int gk0 = k0 + c0s * 8;
        const unsigned short* sA0 = (gk0 < DIN)
            ? (aggnb + (long long)growA0 * DIN + gk0)
            : (xb + (long long)growA0 * DIN + (gk0 - DIN));
        pa0 = *(const uint4*)sA0;
        const unsigned short* sA1 = (gk0 < DIN)
            ? (aggnb + (long long)growA1 * DIN + gk0)
            : (xb + (long long)growA1 * DIN + (gk0 - DIN));
        pa1 = *(const uint4*)sA1;
        pb0 = *(const uint4*)(WT + (long long)(bn + c0r) * 256 + k0 + c0s * 8);
        pb1 = *(const uint4*)(WT + (long long)(bn + c1r) * 256 + k0 + c1s * 8);
    };

    f32x4 acc[4][4];
    #pragma unroll
    for (int i = 0; i < 4; ++i)
        #pragma unroll
        for (int j = 0; j < 4; ++j)
            acc[i][j] = (f32x4){0.f, 0.f, 0.f, 0.f};

    gload(0);
    for (int it = 0; it < 8; ++it) {
        if (it) __syncthreads();
        *(uint4*)(Asm + c0r * LDSP + c0s * 8) = pa0;
        *(uint4*)(Asm + c1r * LDSP + c1s * 8) = pa1;
        *(uint4*)(Bsm + c0r * LDSP + c0s * 8) = pb0;
        *(uint4*)(Bsm + c1r * LDSP + c1s * 8) = pb1;
        __syncthreads();
        if (it < 7) gload((it + 1) * 32);
        bf16x8 af[4], bfr[4];
        #pragma unroll
        for (int mi = 0; mi < 4; ++mi)
            af[mi] = *(const bf16x8*)(Asm + (wr * 64 + mi * 16 + lrow) * LDSP + quad * 8);
        #pragma unroll
        for (int ni = 0; ni < 4; ++ni)
            bfr[ni] = *(const bf16x8*)(Bsm + (wc * 64 + ni * 16 + lrow) * LDSP + quad * 8);
        #pragma unroll
        for (int mi = 0; mi < 4; ++mi)
            #pragma unroll
            for (int ni = 0; ni < 4; ++ni)
                acc[mi][ni] = __builtin_amdgcn_mfma_f32_16x16x32_bf16(
                    af[mi], bfr[ni], acc[mi][ni], 0, 0, 0);
    }
    #pragma unroll
    for (int mi = 0; mi < 4; ++mi) {
        #pragma unroll
        for (int ni = 0; ni < 4; ++ni) {
            int col = bn + wc * 64 + ni * 16 + lrow;
            float bv = bias[col];
            #pragma unroll
            for (int r = 0; r < 4; ++r) {
                int row = bm + wr * 64 + mi * 16 + quad * 4 + r;
                if (row < NMID) {
                    float v = acc[mi][ni][r] + bv;
                    h[(long long)row * DHID + col] = f2bf(fmaxf(v, 0.0f));
                }
            }
        }
    }
}

// p = h @ Wl2 (all rows, bf16 out); q = h @ Wr2 + b2 (rows < NTGT, f32 out).
__global__ __launch_bounds__(256) void gemm2_dual_mfma(
    const unsigned short* __restrict__ h, const unsigned short* __restrict__ WT2,
    const float* __restrict__ b2,
    unsigned short* __restrict__ pb, float* __restrict__ qb)
{
    __shared__ unsigned short Asm[128 * LDSP];
    __shared__ unsigned short Bsm[128 * LDSP];
    const int tid = threadIdx.x;
    const int bm = blockIdx.x * 128;
    const int wave = tid >> 6, lane = tid & 63;
    const int lrow = lane & 15, quad = lane >> 4;
    const bool doq = (bm < NTGT);

    const int c0r = tid >> 2, c0s = tid & 3;
    const int c1r = (tid + 256) >> 2;
    int growA0 = bm + c0r; if (growA0 >= NMID) growA0 = NMID - 1;
    int growA1 = bm + c1r; if (growA1 >= NMID) growA1 = NMID - 1;

    uint4 pa0, pa1, pb0, pb1;
    auto gload = [&](int k0) {
        pa0 = *(const uint4*)(h + (long long)growA0 * DHID + k0 + c0s * 8);
        pa1 = *(const uint4*)(h + (long long)growA1 * DHID + k0 + c0s * 8);
        pb0 = *(const uint4*)(WT2 + (long long)c0r * 256 + k0 + c0s * 8);
        pb1 = *(const uint4*)(WT2 + (long long)c1r * 256 + k0 + c0s * 8);
    };

    f32x4 accP[2][4], accQ[2][4];
    #pragma unroll
    for (int i = 0; i < 2; ++i)
        #pragma unroll
        for (int j = 0; j < 4; ++j) {
            accP[i][j] = (f32x4){0.f, 0.f, 0.f, 0.f};
            accQ[i][j] = (f32x4){0.f, 0.f, 0.f, 0.f};
        }

    gload(0);
    for (int it = 0; it < 8; ++it) {
        if (it) __syncthreads();
        *(uint4*)(Asm + c0r * LDSP + c0s * 8) = pa0;
        *(uint4*)(Asm + c1r * LDSP + c0s * 8) = pa1;
        *(uint4*)(Bsm + c0r * LDSP + c0s * 8) = pb0;
        *(uint4*)(Bsm + c1r * LDSP + c0s * 8) = pb1;
        __syncthreads();
        if (it < 7) gload((it + 1) * 32);
        bf16x8 af[2], bp[4];
        #pragma unroll
        for (int mi = 0; mi < 2; ++mi)
            af[mi] = *(const bf16x8*)(Asm + (wave * 32 + mi * 16 + lrow) * LDSP + quad * 8);
        #pragma unroll
        for (int ni = 0; ni < 4; ++ni)
            bp[ni] = *(const bf16x8*)(Bsm + (ni * 16 + lrow) * LDSP + quad * 8);
        #pragma unroll
        for (int mi = 0; mi < 2; ++mi)
            #pragma unroll
            for (int ni = 0; ni < 4; ++ni)
                accP[mi][ni] = __builtin_amdgcn_mfma_f32_16x16x32_bf16(
                    af[mi], bp[ni], accP[mi][ni], 0, 0, 0);
        if (doq) {
            bf16x8 bq[4];
            #pragma unroll
            for (int ni = 0; ni < 4; ++ni)
                bq[ni] = *(const bf16x8*)(Bsm + (64 + ni * 16 + lrow) * LDSP + quad * 8);
            #pragma unroll
            for (int mi = 0; mi < 2; ++mi)
                #pragma unroll
                for (int ni = 0; ni < 4; ++ni)
                    accQ[mi][ni] = __builtin_amdgcn_mfma_f32_16x16x32_bf16(
                        af[mi], bq[ni], accQ[mi][ni], 0, 0, 0);
        }
    }
    #pragma unroll
    for (int mi = 0; mi < 2; ++mi) {
        #pragma unroll
        for (int ni = 0; ni < 4; ++ni) {
            int col = ni * 16 + lrow;
            #pragma unroll
            for (int r = 0; r < 4; ++r) {
                int row = bm + wave * 32 + mi * 16 + quad * 4 + r;
                if (row < NMID)
                    pb[(long long)row * DOUT + col] = f2bf(accP[mi][ni][r]);
                if (doq && row < NTGT)
                    qb[(long long)row * DOUT + col] = accQ[mi][ni][r] + b2[col];
            }
        }
    }
}

extern "C" void kernel_launch(void* const* d_in, const int* in_sizes, int n_in,
                              void* d_out, int out_size, void* d_ws, size_t ws_size,
                              hipStream_t stream) {
    const float* x   = (const float*)d_in[0];
    const int*   ei1 = (const int*)d_in[1];
    const int*   ei2 = (const int*)d_in[2];
    const float* Wl1 = (const float*)d_in[3];
    const float* Wr1 = (const float*)d_in[4];
    const float* b1  = (const float*)d_in[5];
    const float* Wl2 = (const float*)d_in[6];
    const float* Wr2 = (const float*)d_in[7];
    const float* b2  = (const float*)d_in[8];
    float* out = (float*)d_out;

    unsigned short* xb    = (unsigned short*)d_ws;
    unsigned short* aggnb = xb + (size_t)NSRC * DIN;
    unsigned short* h     = aggnb + (size_t)NMID * DIN;
    unsigned short* WT1   = h + (size_t)NMID * DHID;
    unsigned short* WT2   = WT1 + 256 * 256;
    unsigned short* pb    = WT2 + 128 * 256;              // bf16 p: NMID x 64
    float* qb    = (float*)(pb + (size_t)NMID * DOUT);
    int* rs1     = (int*)(qb + (size_t)NTGT * DOUT);
    int* rs2     = rs1 + (NMID + 1);
    int* bhist1  = rs2 + (NTGT + 1);
    int* bhist2  = bhist1 + NBK1;
    int* donecnt = bhist2 + NBK2;
    int* bbase1  = donecnt + 1;
    int* bbase2  = bbase1 + (NBK1 + 1);
    int* bcur1   = bbase2 + (NBK2 + 1);
    int* bcur2   = bcur1 + NBK1;
    int* csr1    = bcur2 + NBK2 + 1;
    int* csr2    = csr1 + NE1;
    uint2* gbuf1 = (uint2*)(((size_t)(csr2 + NE2) + 15) & ~(size_t)15);
    uint2* gbuf2 = gbuf1 + NE1;

    // zero bhist1, bhist2, donecnt (contiguous)
    hipMemsetAsync(bhist1, 0, (size_t)(NBK1 + NBK2 + 1) * 4, stream);
    conv_hist_kernel<<<NHIST + CVB, 256, 0, stream>>>(
        x, Wl1, Wr1, Wl2, Wr2, xb, WT1, WT2, ei1, ei2, bhist1, bhist2,
        donecnt, bbase1, bbase2, bcur1, bcur2, rs1, rs2);
    bin_kernel<<<NCH1 + NCH2, 256, 0, stream>>>(ei1, ei2, bcur1, bcur2, gbuf1, gbuf2);
    bucket_csr_kernel<<<NBK1 + NBK2, 256, 0, stream>>>(
        gbuf1, gbuf2, bbase1, bbase2, rs1, rs2, csr1, csr2);

    gather1_kernel<<<(NMID + 3) / 4, 256, 0, stream>>>(xb, rs1, csr1, aggnb);
    {
        dim3 grid((NMID + 127) / 128, 2);
        gemm1_mfma<<<grid, 256, 0, stream>>>(aggnb, xb, WT1, b1, h);
    }
    gemm2_dual_mfma<<<(NMID + 127) / 128, 256, 0, stream>>>(h, WT2, b2, pb, qb);
    gather2_final_kernel<<<(NTGT + 3) / 4, 256, 0, stream>>>(pb, qb, rs2, csr2, out);
}

// Round 13
// 388.135 us; speedup vs baseline: 1.0792x; 1.0444x over previous
//
#include <hip/hip_runtime.h>

// GraphSAGE 2-layer. Round 20: EXACT revert to the round-14 source (best
// measured 389.3us). r19's threadfence-fused scan cost ~16us (294 hist
// blocks x __threadfence => cross-XCD L2 writebacks thrash the streaming
// convert; conv_hist 60->76us). Fences inside wide kernels are NOT free on
// 8-XCD MI355X — kernel-boundary ordering is cheaper. Structure: fused
// conv+hist (no fence), separate bucket_scan, bin, bucket_csr (both layers),
// r8 gather1 (VGPR12/LDS0, full occupancy), r14 gemm1 (grid.y=2),
// gemm2_dual (bf16 p), r14 gather2 (4-wide).

#define NSRC 200000
#define NMID 100000
#define NTGT 50000
#define NE1  1600000
#define NE2  800000
#define DIN  128
#define DHID 256
#define DOUT 64

#define XCH (NSRC * 16)

#define CH   4096
#define NBK1 391
#define NBK2 196
#define NCH1 ((NE1 + CH - 1) / CH)
#define NCH2 ((NE2 + CH - 1) / CH)
#define HCH  8192
#define NHC1 ((NE1 + HCH - 1) / HCH)
#define NHC2 ((NE2 + HCH - 1) / HCH)
#define NHIST (NHC1 + NHC2)
#define CVB ((XCH + 65536 + 32768 + 255) / 256)
#define MAXBUF 6144

typedef __attribute__((ext_vector_type(8))) short bf16x8;
typedef __attribute__((ext_vector_type(4))) float f32x4;
typedef __attribute__((ext_vector_type(2))) float f32x2;

__device__ __forceinline__ unsigned short f2bf(float f) {
    unsigned int u = __builtin_bit_cast(unsigned int, f);
    u += 0x7FFFu + ((u >> 16) & 1u);
    return (unsigned short)(u >> 16);
}
__device__ __forceinline__ float bf_lo(unsigned int u) {
    return __builtin_bit_cast(float, u << 16);
}
__device__ __forceinline__ float bf_hi(unsigned int u) {
    return __builtin_bit_cast(float, u & 0xFFFF0000u);
}
__device__ __forceinline__ float bf1(unsigned short u) {
    return __builtin_bit_cast(float, (unsigned int)u << 16);
}

// ---------------- fused convert + bucket hist (no fence, no scan) ----------
__global__ __launch_bounds__(256) void conv_hist_kernel(
    const float* __restrict__ x,
    const float* __restrict__ Wl1, const float* __restrict__ Wr1,
    const float* __restrict__ Wl2, const float* __restrict__ Wr2,
    unsigned short* __restrict__ xb, unsigned short* __restrict__ WT1,
    unsigned short* __restrict__ WT2,
    const int* __restrict__ ei1, const int* __restrict__ ei2,
    int* __restrict__ bhist1, int* __restrict__ bhist2)
{
    __shared__ unsigned int lh[512];
    if (blockIdx.x < NHIST) {
        // ---- bucket histogram branch ----
        const int* ei; int* bh; int nE, nbk, chunk;
        if (blockIdx.x < NHC1) { ei = ei1; bh = bhist1; nE = NE1; nbk = NBK1; chunk = blockIdx.x; }
        else { ei = ei2; bh = bhist2; nE = NE2; nbk = NBK2; chunk = blockIdx.x - NHC1; }
        int t = threadIdx.x;
        lh[t] = 0; lh[t + 256] = 0;
        __syncthreads();
        int base = chunk * HCH;
        int end = nE < base + HCH ? nE : base + HCH;
        for (int e = base + t; e < end; e += 256)
            atomicAdd(&lh[((unsigned)ei[nE + e]) >> 8], 1u);
        __syncthreads();
        if (t < nbk && lh[t]) atomicAdd(&bh[t], (int)lh[t]);
        if (t + 256 < nbk && lh[t + 256]) atomicAdd(&bh[t + 256], (int)lh[t + 256]);
        return;
    }
    // ---- convert branch ----
    int gid = (blockIdx.x - NHIST) * 256 + threadIdx.x;
    if (gid < XCH) {
        const float4 v0 = *(const float4*)(x + (long long)gid * 8);
        const float4 v1 = *(const float4*)(x + (long long)gid * 8 + 4);
        unsigned short o[8] = {f2bf(v0.x), f2bf(v0.y), f2bf(v0.z), f2bf(v0.w),
                               f2bf(v1.x), f2bf(v1.y), f2bf(v1.z), f2bf(v1.w)};
        *(uint4*)(xb + (long long)gid * 8) = *(const uint4*)o;
        return;
    }
    int g = gid - XCH;
    if (g < 65536) {
        int n = g >> 8, k = g & 255;
        float v = (k < DIN) ? Wl1[(long long)k * DHID + n]
                            : Wr1[(long long)(k - DIN) * DHID + n];
        WT1[g] = f2bf(v);
        return;
    }
    g -= 65536;
    if (g < 32768) {
        int n2 = g >> 8, k = g & 255;
        float v = (n2 < DOUT) ? Wl2[(long long)k * DOUT + n2]
                              : Wr2[(long long)k * DOUT + (n2 - DOUT)];
        WT2[g] = f2bf(v);
    }
}

// ---------------- bucket-first CSR build ----------------

__global__ __launch_bounds__(256) void bucket_scan_kernel(
    const int* __restrict__ bhist1, const int* __restrict__ bhist2,
    int* __restrict__ bbase1, int* __restrict__ bbase2,
    int* __restrict__ bcur1, int* __restrict__ bcur2,
    int* __restrict__ rs1, int* __restrict__ rs2)
{
    __shared__ int s[256];
    int t = threadIdx.x;
    int a0 = (2 * t < NBK1) ? bhist1[2 * t] : 0;
    int a1 = (2 * t + 1 < NBK1) ? bhist1[2 * t + 1] : 0;
    s[t] = a0 + a1;
    __syncthreads();
    for (int off = 1; off < 256; off <<= 1) {
        int u = (t >= off) ? s[t - off] : 0;
        __syncthreads();
        s[t] += u;
        __syncthreads();
    }
    int ex = (t > 0) ? s[t - 1] : 0;
    if (2 * t < NBK1)     { bbase1[2 * t] = ex;      bcur1[2 * t] = ex; }
    if (2 * t + 1 < NBK1) { bbase1[2 * t + 1] = ex + a0; bcur1[2 * t + 1] = ex + a0; }
    if (t == 0) { bbase1[NBK1] = NE1; rs1[NMID] = NE1; bbase2[NBK2] = NE2; rs2[NTGT] = NE2; }
    __syncthreads();
    int b0 = (t < NBK2) ? bhist2[t] : 0;
    s[t] = b0;
    __syncthreads();
    for (int off = 1; off < 256; off <<= 1) {
        int u = (t >= off) ? s[t - off] : 0;
        __syncthreads();
        s[t] += u;
        __syncthreads();
    }
    int ex2 = (t > 0) ? s[t - 1] : 0;
    if (t < NBK2) { bbase2[t] = ex2; bcur2[t] = ex2; }
}

__global__ __launch_bounds__(256) void bin_kernel(
    const int* __restrict__ ei1, const int* __restrict__ ei2,
    int* __restrict__ bcur1, int* __restrict__ bcur2,
    uint2* __restrict__ gbuf1, uint2* __restrict__ gbuf2)
{
    __shared__ unsigned int lcnt[512];
    __shared__ unsigned int lofs[512];
    __shared__ unsigned int lpos[512];
    __shared__ unsigned int gbase[512];
    __shared__ unsigned int swarp[256];
    __shared__ uint2 lbuf[CH];

    const int* ei; int* bcur; uint2* gbuf; int nE, nbk, chunk;
    if (blockIdx.x < NCH1) {
        ei = ei1; bcur = bcur1; gbuf = gbuf1; nE = NE1; nbk = NBK1; chunk = blockIdx.x;
    } else {
        ei = ei2; bcur = bcur2; gbuf = gbuf2; nE = NE2; nbk = NBK2; chunk = blockIdx.x - NCH1;
    }
    int base = chunk * CH;
    int nb = nE - base; if (nb > CH) nb = CH;
    int t = threadIdx.x;

    for (int i = t; i < 512; i += 256) { lcnt[i] = 0; lpos[i] = 0; }
    __syncthreads();

    int srcv[16], tgtv[16];
    #pragma unroll
    for (int i = 0; i < 16; ++i) {
        int e = base + i * 256 + t;
        if (e < nE) {
            tgtv[i] = ei[nE + e];
            srcv[i] = ei[e];
            atomicAdd(&lcnt[tgtv[i] >> 8], 1u);
        } else tgtv[i] = -1;
    }
    __syncthreads();

    unsigned a0 = lcnt[2 * t], a1 = lcnt[2 * t + 1];
    swarp[t] = a0 + a1;
    __syncthreads();
    for (int off = 1; off < 256; off <<= 1) {
        unsigned v = (t >= off) ? swarp[t - off] : 0;
        __syncthreads();
        swarp[t] += v;
        __syncthreads();
    }
    unsigned ex = (t > 0) ? swarp[t - 1] : 0;
    lofs[2 * t] = ex;
    lofs[2 * t + 1] = ex + a0;
    if (2 * t < nbk && a0) gbase[2 * t] = atomicAdd(&bcur[2 * t], (int)a0);
    if (2 * t + 1 < nbk && a1) gbase[2 * t + 1] = atomicAdd(&bcur[2 * t + 1], (int)a1);
    __syncthreads();

    #pragma unroll
    for (int i = 0; i < 16; ++i) {
        if (tgtv[i] >= 0) {
            int b = tgtv[i] >> 8;
            unsigned idx = lofs[b] + atomicAdd(&lpos[b], 1u);
            lbuf[idx] = make_uint2((unsigned)srcv[i], (unsigned)tgtv[i]);
        }
    }
    __syncthreads();

    for (int i = t; i < nb; i += 256) {
        uint2 r = lbuf[i];
        int b = (int)(r.y >> 8);
        unsigned gi = gbase[b] + ((unsigned)i - lofs[b]);
        gbuf[gi] = r;
    }
}

__global__ __launch_bounds__(256) void bucket_csr_kernel(
    const uint2* __restrict__ gbuf1, const uint2* __restrict__ gbuf2,
    const int* __restrict__ bbase1, const int* __restrict__ bbase2,
    int* __restrict__ rs1, int* __restrict__ rs2,
    int* __restrict__ csr1, int* __restrict__ csr2)
{
    __shared__ unsigned int lhist[256];
    __shared__ unsigned int lcur[256];
    __shared__ unsigned int sscan[256];
    __shared__ unsigned int lbuf[MAXBUF];
    const uint2* gbuf; const int* bbase; int* rs; int* csr; int bucket, ntot;
    if (blockIdx.x < NBK1) {
        gbuf = gbuf1; bbase = bbase1; rs = rs1; csr = csr1; bucket = blockIdx.x; ntot = NMID;
    } else {
        gbuf = gbuf2; bbase = bbase2; rs = rs2; csr = csr2; bucket = blockIdx.x - NBK1; ntot = NTGT;
    }
    int base = bbase[bucket];
    int size = bbase[bucket + 1] - base;
    int node0 = bucket << 8;
    int nnode = ntot - node0; if (nnode > 256) nnode = 256;
    int t = threadIdx.x;
    lhist[t] = 0;
    __syncthreads();
    for (int i = t; i < size; i += 256)
        atomicAdd(&lhist[gbuf[base + i].y & 255], 1u);
    __syncthreads();
    unsigned v = lhist[t];
    sscan[t] = v;
    __syncthreads();
    for (int off = 1; off < 256; off <<= 1) {
        unsigned u = (t >= off) ? sscan[t - off] : 0;
        __syncthreads();
        sscan[t] += u;
        __syncthreads();
    }
    unsigned ex = (t > 0) ? sscan[t - 1] : 0;
    lcur[t] = ex;
    if (t < nnode) rs[node0 + t] = base + (int)ex;
    __syncthreads();
    for (int i = t; i < size; i += 256) {
        uint2 r = gbuf[base + i];
        unsigned pos = atomicAdd(&lcur[r.y & 255], 1u);
        lbuf[pos] = r.x;
    }
    __syncthreads();
    for (int i = t; i < size; i += 256)
        csr[base + i] = (int)lbuf[i];
}

// ---------------- gathers (round-8 form: scalarized, 4-wide) ----------------
// One wave per node. node forced into SGPR so rs/csr reads are s_load and row
// loads use the saddr form (zero per-edge VALU address math).

__global__ __launch_bounds__(256) void gather1_kernel(
    const unsigned short* __restrict__ xb, const int* __restrict__ rs,
    const int* __restrict__ csr, unsigned short* __restrict__ aggnb)
{
    int wid = threadIdx.x >> 6;
    int lane = threadIdx.x & 63;
    int node = __builtin_amdgcn_readfirstlane(blockIdx.x * 4 + wid);
    if (node >= NMID) return;
    int s = rs[node];
    int d = rs[node + 1] - s;
    const unsigned int* xw = (const unsigned int*)xb;   // 64 uints per row
    f32x2 a0 = {0.f, 0.f}, a1 = {0.f, 0.f}, a2 = {0.f, 0.f}, a3 = {0.f, 0.f};
    int j = 0;
    for (; j + 3 < d; j += 4) {
        int i0 = csr[s + j];
        int i1 = csr[s + j + 1];
        int i2 = csr[s + j + 2];
        int i3 = csr[s + j + 3];
        unsigned int u0 = xw[((size_t)(unsigned)i0 << 6) + lane];
        unsigned int u1 = xw[((size_t)(unsigned)i1 << 6) + lane];
        unsigned int u2 = xw[((size_t)(unsigned)i2 << 6) + lane];
        unsigned int u3 = xw[((size_t)(unsigned)i3 << 6) + lane];
        a0 += (f32x2){bf_lo(u0), bf_hi(u0)};
        a1 += (f32x2){bf_lo(u1), bf_hi(u1)};
        a2 += (f32x2){bf_lo(u2), bf_hi(u2)};
        a3 += (f32x2){bf_lo(u3), bf_hi(u3)};
    }
    for (; j < d; ++j) {
        int i0 = csr[s + j];
        unsigned int u0 = xw[((size_t)(unsigned)i0 << 6) + lane];
        a0 += (f32x2){bf_lo(u0), bf_hi(u0)};
    }
    float inv = (d > 0) ? 1.0f / (float)d : 0.f;
    f32x2 r = (a0 + a1) + (a2 + a3);
    float r0 = r.x * inv;
    float r1 = r.y * inv;
    unsigned int packed = (unsigned int)f2bf(r0) | ((unsigned int)f2bf(r1) << 16);
    *(unsigned int*)(aggnb + (long long)node * DIN + lane * 2) = packed;
}

// out[node] = q[node] + mean_{src in N(node)} p[src]; p is bf16 (64/row)
__global__ __launch_bounds__(256) void gather2_final_kernel(
    const unsigned short* __restrict__ pb, const float* __restrict__ qb,
    const int* __restrict__ rs, const int* __restrict__ csr,
    float* __restrict__ out)
{
    int wid = threadIdx.x >> 6;
    int lane = threadIdx.x & 63;
    int node = __builtin_amdgcn_readfirstlane(blockIdx.x * 4 + wid);
    if (node >= NTGT) return;
    int s = rs[node];
    int d = rs[node + 1] - s;
    float a0 = 0.f, a1 = 0.f, a2 = 0.f, a3 = 0.f;
    int j = 0;
    for (; j + 3 < d; j += 4) {
        int i0 = csr[s + j];
        int i1 = csr[s + j + 1];
        int i2 = csr[s + j + 2];
        int i3 = csr[s + j + 3];
        a0 += bf1(pb[((size_t)(unsigned)i0 << 6) + lane]);
        a1 += bf1(pb[((size_t)(unsigned)i1 << 6) + lane]);
        a2 += bf1(pb[((size_t)(unsigned)i2 << 6) + lane]);
        a3 += bf1(pb[((size_t)(unsigned)i3 << 6) + lane]);
    }
    for (; j < d; ++j) {
        int i0 = csr[s + j];
        a0 += bf1(pb[((size_t)(unsigned)i0 << 6) + lane]);
    }
    float inv = (d > 0) ? 1.0f / (float)d : 0.f;
    out[(long long)node * DOUT + lane] =
        qb[(long long)node * DOUT + lane] + ((a0 + a1) + (a2 + a3)) * inv;
}

// ---------------- MFMA GEMMs ----------------
#define LDSP 40

// h = relu([aggnb|xb] @ WT1^T + b1), register-prefetch pipelined
__global__ __launch_bounds__(256) void gemm1_mfma(
    const unsigned short* __restrict__ aggnb, const unsigned short* __restrict__ xb,
    const unsigned short* __restrict__ WT, const float* __restrict__ bias,
    unsigned short* __restrict__ h)
{
    __shared__ unsigned short Asm[128 * LDSP];
    __shared__ unsigned short Bsm[128 * LDSP];
    const int tid = threadIdx.x;
    const int bm = blockIdx.x * 128;
    const int bn = blockIdx.y * 128;
    const int wave = tid >> 6, lane = tid & 63;
    const int wr = wave >> 1, wc = wave & 1;
    const int lrow = lane & 15, quad = lane >> 4;

    const int c0r = tid >> 2, c0s = tid & 3;
    const int c1r = (tid + 256) >> 2, c1s = tid & 3;
    int growA0 = bm + c0r; if (growA0 >= NMID) growA0 = NMID - 1;
    int growA1 = bm + c1r; if (growA1 >= NMID) growA1 = NMID - 1;

    uint4 pa0, pa1, pb0, pb1;
    auto gload = [&](int k0) {
        int gk0 = k0 + c0s * 8;
        const unsigned short* sA0 = (gk0 < DIN)
            ? (aggnb + (long long)growA0 * DIN + gk0)
            : (xb + (long long)growA0 * DIN + (gk0 - DIN));
        pa0 = *(const uint4*)sA0;
        const unsigned short* sA1 = (gk0 < DIN)
            ? (aggnb + (long long)growA1 * DIN + gk0)
            : (xb + (long long)growA1 * DIN + (gk0 - DIN));
        pa1 = *(const uint4*)sA1;
        pb0 = *(const uint4*)(WT + (long long)(bn + c0r) * 256 + k0 + c0s * 8);
        pb1 = *(const uint4*)(WT + (long long)(bn + c1r) * 256 + k0 + c1s * 8);
    };

    f32x4 acc[4][4];
    #pragma unroll
    for (int i = 0; i < 4; ++i)
        #pragma unroll
        for (int j = 0; j < 4; ++j)
            acc[i][j] = (f32x4){0.f, 0.f, 0.f, 0.f};

    gload(0);
    for (int it = 0; it < 8; ++it) {
        if (it) __syncthreads();
        *(uint4*)(Asm + c0r * LDSP + c0s * 8) = pa0;
        *(uint4*)(Asm + c1r * LDSP + c1s * 8) = pa1;
        *(uint4*)(Bsm + c0r * LDSP + c0s * 8) = pb0;
        *(uint4*)(Bsm + c1r * LDSP + c1s * 8) = pb1;
        __syncthreads();
        if (it < 7) gload((it + 1) * 32);
        bf16x8 af[4], bfr[4];
        #pragma unroll
        for (int mi = 0; mi < 4; ++mi)
            af[mi] = *(const bf16x8*)(Asm + (wr * 64 + mi * 16 + lrow) * LDSP + quad * 8);
        #pragma unroll
        for (int ni = 0; ni < 4; ++ni)
            bfr[ni] = *(const bf16x8*)(Bsm + (wc * 64 + ni * 16 + lrow) * LDSP + quad * 8);
        #pragma unroll
        for (int mi = 0; mi < 4; ++mi)
            #pragma unroll
            for (int ni = 0; ni < 4; ++ni)
                acc[mi][ni] = __builtin_amdgcn_mfma_f32_16x16x32_bf16(
                    af[mi], bfr[ni], acc[mi][ni], 0, 0, 0);
    }
    #pragma unroll
    for (int mi = 0; mi < 4; ++mi) {
        #pragma unroll
        for (int ni = 0; ni < 4; ++ni) {
            int col = bn + wc * 64 + ni * 16 + lrow;
            float bv = bias[col];
            #pragma unroll
            for (int r = 0; r < 4; ++r) {
                int row = bm + wr * 64 + mi * 16 + quad * 4 + r;
                if (row < NMID) {
                    float v = acc[mi][ni][r] + bv;
                    h[(long long)row * DHID + col] = f2bf(fmaxf(v, 0.0f));
                }
            }
        }
    }
}

// p = h @ Wl2 (all rows, bf16 out); q = h @ Wr2 + b2 (rows < NTGT, f32 out).
// WT2: 128 n-rows x 256 k.
__global__ __launch_bounds__(256) void gemm2_dual_mfma(
    const unsigned short* __restrict__ h, const unsigned short* __restrict__ WT2,
    const float* __restrict__ b2,
    unsigned short* __restrict__ pb, float* __restrict__ qb)
{
    __shared__ unsigned short Asm[128 * LDSP];
    __shared__ unsigned short Bsm[128 * LDSP];
    const int tid = threadIdx.x;
    const int bm = blockIdx.x * 128;
    const int wave = tid >> 6, lane = tid & 63;
    const int lrow = lane & 15, quad = lane >> 4;
    const bool doq = (bm < NTGT);

    const int c0r = tid >> 2, c0s = tid & 3;
    const int c1r = (tid + 256) >> 2;
    int growA0 = bm + c0r; if (growA0 >= NMID) growA0 = NMID - 1;
    int growA1 = bm + c1r; if (growA1 >= NMID) growA1 = NMID - 1;

    uint4 pa0, pa1, pb0, pb1;
    auto gload = [&](int k0) {
        pa0 = *(const uint4*)(h + (long long)growA0 * DHID + k0 + c0s * 8);
        pa1 = *(const uint4*)(h + (long long)growA1 * DHID + k0 + c0s * 8);
        pb0 = *(const uint4*)(WT2 + (long long)c0r * 256 + k0 + c0s * 8);
        pb1 = *(const uint4*)(WT2 + (long long)c1r * 256 + k0 + c0s * 8);
    };

    f32x4 accP[2][4], accQ[2][4];
    #pragma unroll
    for (int i = 0; i < 2; ++i)
        #pragma unroll
        for (int j = 0; j < 4; ++j) {
            accP[i][j] = (f32x4){0.f, 0.f, 0.f, 0.f};
            accQ[i][j] = (f32x4){0.f, 0.f, 0.f, 0.f};
        }

    gload(0);
    for (int it = 0; it < 8; ++it) {
        if (it) __syncthreads();
        *(uint4*)(Asm + c0r * LDSP + c0s * 8) = pa0;
        *(uint4*)(Asm + c1r * LDSP + c0s * 8) = pa1;
        *(uint4*)(Bsm + c0r * LDSP + c0s * 8) = pb0;
        *(uint4*)(Bsm + c1r * LDSP + c0s * 8) = pb1;
        __syncthreads();
        if (it < 7) gload((it + 1) * 32);
        bf16x8 af[2], bp[4];
        #pragma unroll
        for (int mi = 0; mi < 2; ++mi)
            af[mi] = *(const bf16x8*)(Asm + (wave * 32 + mi * 16 + lrow) * LDSP + quad * 8);
        #pragma unroll
        for (int ni = 0; ni < 4; ++ni)
            bp[ni] = *(const bf16x8*)(Bsm + (ni * 16 + lrow) * LDSP + quad * 8);
        #pragma unroll
        for (int mi = 0; mi < 2; ++mi)
            #pragma unroll
            for (int ni = 0; ni < 4; ++ni)
                accP[mi][ni] = __builtin_amdgcn_mfma_f32_16x16x32_bf16(
                    af[mi], bp[ni], accP[mi][ni], 0, 0, 0);
        if (doq) {
            bf16x8 bq[4];
            #pragma unroll
            for (int ni = 0; ni < 4; ++ni)
                bq[ni] = *(const bf16x8*)(Bsm + (64 + ni * 16 + lrow) * LDSP + quad * 8);
            #pragma unroll
            for (int mi = 0; mi < 2; ++mi)
                #pragma unroll
                for (int ni = 0; ni < 4; ++ni)
                    accQ[mi][ni] = __builtin_amdgcn_mfma_f32_16x16x32_bf16(
                        af[mi], bq[ni], accQ[mi][ni], 0, 0, 0);
        }
    }
    #pragma unroll
    for (int mi = 0; mi < 2; ++mi) {
        #pragma unroll
        for (int ni = 0; ni < 4; ++ni) {
            int col = ni * 16 + lrow;
            #pragma unroll
            for (int r = 0; r < 4; ++r) {
                int row = bm + wave * 32 + mi * 16 + quad * 4 + r;
                if (row < NMID)
                    pb[(long long)row * DOUT + col] = f2bf(accP[mi][ni][r]);
                if (doq && row < NTGT)
                    qb[(long long)row * DOUT + col] = accQ[mi][ni][r] + b2[col];
            }
        }
    }
}

extern "C" void kernel_launch(void* const* d_in, const int* in_sizes, int n_in,
                              void* d_out, int out_size, void* d_ws, size_t ws_size,
                              hipStream_t stream) {
    const float* x   = (const float*)d_in[0];
    const int*   ei1 = (const int*)d_in[1];
    const int*   ei2 = (const int*)d_in[2];
    const float* Wl1 = (const float*)d_in[3];
    const float* Wr1 = (const float*)d_in[4];
    const float* b1  = (const float*)d_in[5];
    const float* Wl2 = (const float*)d_in[6];
    const float* Wr2 = (const float*)d_in[7];
    const float* b2  = (const float*)d_in[8];
    float* out = (float*)d_out;

    unsigned short* xb    = (unsigned short*)d_ws;
    unsigned short* aggnb = xb + (size_t)NSRC * DIN;
    unsigned short* h     = aggnb + (size_t)NMID * DIN;
    unsigned short* WT1   = h + (size_t)NMID * DHID;
    unsigned short* WT2   = WT1 + 256 * 256;
    unsigned short* pb    = WT2 + 128 * 256;              // bf16 p: NMID x 64
    float* qb   = (float*)(pb + (size_t)NMID * DOUT);
    int* rs1    = (int*)(qb + (size_t)NTGT * DOUT);
    int* rs2    = rs1 + (NMID + 1);
    int* bhist1 = rs2 + (NTGT + 1);
    int* bhist2 = bhist1 + NBK1;
    int* bbase1 = bhist2 + NBK2;
    int* bbase2 = bbase1 + (NBK1 + 1);
    int* bcur1  = bbase2 + (NBK2 + 1);
    int* bcur2  = bcur1 + NBK1;
    int* csr1   = bcur2 + NBK2 + 1;
    int* csr2   = csr1 + NE1;
    uint2* gbuf1 = (uint2*)(((size_t)(csr2 + NE2) + 15) & ~(size_t)15);
    uint2* gbuf2 = gbuf1 + NE1;

    hipMemsetAsync(bhist1, 0, (size_t)(NBK1 + NBK2) * 4, stream);
    conv_hist_kernel<<<NHIST + CVB, 256, 0, stream>>>(
        x, Wl1, Wr1, Wl2, Wr2, xb, WT1, WT2, ei1, ei2, bhist1, bhist2);
    bucket_scan_kernel<<<1, 256, 0, stream>>>(bhist1, bhist2, bbase1, bbase2,
                                              bcur1, bcur2, rs1, rs2);
    bin_kernel<<<NCH1 + NCH2, 256, 0, stream>>>(ei1, ei2, bcur1, bcur2, gbuf1, gbuf2);
    bucket_csr_kernel<<<NBK1 + NBK2, 256, 0, stream>>>(
        gbuf1, gbuf2, bbase1, bbase2, rs1, rs2, csr1, csr2);

    gather1_kernel<<<(NMID + 3) / 4, 256, 0, stream>>>(xb, rs1, csr1, aggnb);
    {
        dim3 grid((NMID + 127) / 128, 2);
        gemm1_mfma<<<grid, 256, 0, stream>>>(aggnb, xb, WT1, b1, h);
    }
    gemm2_dual_mfma<<<(NMID + 127) / 128, 256, 0, stream>>>(h, WT2, b2, pb, qb);
    gather2_final_kernel<<<(NTGT + 3) / 4, 256, 0, stream>>>(pb, qb, rs2, csr2, out);
}